// Round 1
// baseline (753.434 us; speedup 1.0000x reference)
//
#include <hip/hip_runtime.h>
#include <math.h>

#define NTOK 32768   // N = B*S
#define BB   64
#define SS   512
#define DD   512
#define UU   512
#define LL   48
#define DEGQ 2

#define BM 128
#define BN 128
#define BK 16
#define LDP 132      // padded LDS leading dim (16B-aligned, breaks bank conflicts)

__device__ __forceinline__ float sigm(float x) { return 1.0f / (1.0f + expf(-x)); }

// ---------------------------------------------------------------------------
// Kernel 1: gate GEMVs.  g_*[n] = x[n] . vgate  for the three gate vectors.
// x[n,d] = enc[s, b, d] with n = b*S + s  (enc is (S,B,D) f32).
// One wave (64 lanes) per row; 4 rows per 256-thread block.
// ---------------------------------------------------------------------------
__global__ __launch_bounds__(256) void gates_kernel(
    const float* __restrict__ enc,
    const float* __restrict__ vg_in,
    const float* __restrict__ vg_out,
    const float* __restrict__ vg_self,
    float* __restrict__ g_in, float* __restrict__ g_out, float* __restrict__ g_self)
{
    const int wave = threadIdx.x >> 6;
    const int lane = threadIdx.x & 63;
    const int n = blockIdx.x * 4 + wave;
    const int b = n >> 9;          // n / S
    const int s = n & 511;         // n % S
    const float* xrow = enc + (size_t)s * (BB * DD) + (size_t)b * DD;

    float4 xa = *(const float4*)(xrow + lane * 8);
    float4 xb = *(const float4*)(xrow + lane * 8 + 4);

    float4 ga = *(const float4*)(vg_in + lane * 8);
    float4 gb = *(const float4*)(vg_in + lane * 8 + 4);
    float di = xa.x*ga.x + xa.y*ga.y + xa.z*ga.z + xa.w*ga.w
             + xb.x*gb.x + xb.y*gb.y + xb.z*gb.z + xb.w*gb.w;

    ga = *(const float4*)(vg_out + lane * 8);
    gb = *(const float4*)(vg_out + lane * 8 + 4);
    float dq = xa.x*ga.x + xa.y*ga.y + xa.z*ga.z + xa.w*ga.w
             + xb.x*gb.x + xb.y*gb.y + xb.z*gb.z + xb.w*gb.w;

    ga = *(const float4*)(vg_self + lane * 8);
    gb = *(const float4*)(vg_self + lane * 8 + 4);
    float ds = xa.x*ga.x + xa.y*ga.y + xa.z*ga.z + xa.w*ga.w
             + xb.x*gb.x + xb.y*gb.y + xb.z*gb.z + xb.w*gb.w;

    #pragma unroll
    for (int off = 32; off > 0; off >>= 1) {
        di += __shfl_xor(di, off);
        dq += __shfl_xor(dq, off);
        ds += __shfl_xor(ds, off);
    }
    if (lane == 0) { g_in[n] = di; g_out[n] = dq; g_self[n] = ds; }
}

// ---------------------------------------------------------------------------
// Kernel 2: tiled f32 GEMM  P = x @ W  for W in {V_in, V_out, W_self}.
// grid = (NTOK/BM, 12); blockIdx.y: [mat 0..2] x [4 col tiles of 128].
// 256 threads, each computes an 8x8 micro-tile split 4+4 at 64-offset
// (LDS read aliasing <= 2-way, which is free on gfx950).
// ---------------------------------------------------------------------------
__global__ __launch_bounds__(256) void proj_gemm(
    const float* __restrict__ enc,
    const float* __restrict__ V_in,
    const float* __restrict__ V_out,
    const float* __restrict__ W_self,
    float* __restrict__ P_in, float* __restrict__ P_out, float* __restrict__ P_self)
{
    __shared__ float As[BK][LDP];   // transposed: As[k][m]
    __shared__ float Bs[BK][LDP];   // Bs[k][u]

    const int t   = threadIdx.x;
    const int mat = blockIdx.y >> 2;
    const int u0  = (blockIdx.y & 3) * BN;
    const float* W = (mat == 0) ? V_in : (mat == 1) ? V_out : W_self;
    float*       P = (mat == 0) ? P_in : (mat == 1) ? P_out : P_self;

    const int n0 = blockIdx.x * BM;
    const int b  = n0 >> 9;
    const int s0 = n0 & 511;
    // row (n0+m) of x lives at enc + (s0+m)*B*D + b*D   (all 128 rows share b)
    const float* Abase = enc + (size_t)s0 * (BB * DD) + (size_t)b * DD;

    // A-load assignment: 4 lanes per row (float4 of k), rows m and m+64
    const int am = t >> 2;          // 0..63
    const int ak = (t & 3) * 4;     // k offset within BK
    // B-load assignment: 32 lanes per k-row (float4 of u), rows kr and kr+8
    const int bk = t >> 5;          // 0..7
    const int bc = (t & 31) * 4;    // u offset within BN

    const int tx = t & 15;          // micro-tile col group
    const int ty = t >> 4;          // micro-tile row group

    float acc[8][8];
    #pragma unroll
    for (int i = 0; i < 8; ++i)
        #pragma unroll
        for (int j = 0; j < 8; ++j) acc[i][j] = 0.0f;

    for (int k0 = 0; k0 < DD; k0 += BK) {
        float4 av0 = *(const float4*)(Abase + (size_t)am        * (BB * DD) + k0 + ak);
        float4 av1 = *(const float4*)(Abase + (size_t)(am + 64) * (BB * DD) + k0 + ak);
        float4 bv0 = *(const float4*)(W + (size_t)(k0 + bk)     * UU + u0 + bc);
        float4 bv1 = *(const float4*)(W + (size_t)(k0 + bk + 8) * UU + u0 + bc);

        As[ak + 0][am]      = av0.x;
        As[ak + 1][am]      = av0.y;
        As[ak + 2][am]      = av0.z;
        As[ak + 3][am]      = av0.w;
        As[ak + 0][am + 64] = av1.x;
        As[ak + 1][am + 64] = av1.y;
        As[ak + 2][am + 64] = av1.z;
        As[ak + 3][am + 64] = av1.w;
        *(float4*)&Bs[bk][bc]     = bv0;
        *(float4*)&Bs[bk + 8][bc] = bv1;
        __syncthreads();

        #pragma unroll
        for (int kk = 0; kk < BK; ++kk) {
            float4 a0 = *(const float4*)&As[kk][ty * 4];
            float4 a1 = *(const float4*)&As[kk][64 + ty * 4];
            float4 b0 = *(const float4*)&Bs[kk][tx * 4];
            float4 b1 = *(const float4*)&Bs[kk][64 + tx * 4];
            float ar[8] = {a0.x, a0.y, a0.z, a0.w, a1.x, a1.y, a1.z, a1.w};
            float br[8] = {b0.x, b0.y, b0.z, b0.w, b1.x, b1.y, b1.z, b1.w};
            #pragma unroll
            for (int i = 0; i < 8; ++i)
                #pragma unroll
                for (int j = 0; j < 8; ++j)
                    acc[i][j] = fmaf(ar[i], br[j], acc[i][j]);
        }
        __syncthreads();
    }

    // epilogue: coalesced float4 stores
    #pragma unroll
    for (int hr = 0; hr < 2; ++hr) {
        #pragma unroll
        for (int i = 0; i < 4; ++i) {
            const size_t row = (size_t)n0 + hr * 64 + ty * 4 + i;
            #pragma unroll
            for (int hc = 0; hc < 2; ++hc) {
                float4 v;
                v.x = acc[hr * 4 + i][hc * 4 + 0];
                v.y = acc[hr * 4 + i][hc * 4 + 1];
                v.z = acc[hr * 4 + i][hc * 4 + 2];
                v.w = acc[hr * 4 + i][hc * 4 + 3];
                *(float4*)(P + row * UU + u0 + hc * 64 + tx * 4) = v;
            }
        }
    }
}

// ---------------------------------------------------------------------------
// Kernel 3: gather + gate + combine + LeakyReLU.
// 2 rows per 256-thread block; 128 threads per row, float4 per thread.
// Faithful semantics: in_gate uses UN-gathered x@V_in_gate; out_gate is
// gathered through idx_out; biases added after gather with token's label;
// weights = mask^2 * sigmoid(gate).
// ---------------------------------------------------------------------------
__global__ __launch_bounds__(256) void combine_kernel(
    const float* __restrict__ P_in,  const float* __restrict__ P_out,
    const float* __restrict__ P_self,
    const float* __restrict__ g_in,  const float* __restrict__ g_out,
    const float* __restrict__ g_self,
    const int* __restrict__ arc_in,  const int* __restrict__ arc_out,
    const int* __restrict__ lab_in,  const int* __restrict__ lab_out,
    const float* __restrict__ mask_in, const float* __restrict__ mask_out,
    const float* __restrict__ mask_loop,
    const float* __restrict__ b_in,  const float* __restrict__ b_in_gate,
    const float* __restrict__ b_out, const float* __restrict__ b_out_gate,
    float* __restrict__ out)
{
    const int t    = threadIdx.x;
    const int rowl = t >> 7;              // 0..1
    const int c    = (t & 127) * 4;       // column (float4)
    const int n    = blockIdx.x * 2 + rowl;

    const int l_in = lab_in[n];
    const int ii   = arc_in[n] * SS + arc_in[NTOK + n];
    float w0 = mask_in[n];
    w0 = w0 * w0 * sigm(g_in[n] + b_in_gate[l_in]);     // UN-gathered gate input

    const int m0  = n * DEGQ, m1 = m0 + 1;
    const int lo0 = lab_out[m0], lo1 = lab_out[m1];
    const int io0 = arc_out[m0] * SS + arc_out[NTOK * DEGQ + m0];
    const int io1 = arc_out[m1] * SS + arc_out[NTOK * DEGQ + m1];
    float w1 = mask_out[m0];
    w1 = w1 * w1 * sigm(g_out[io0] + b_out_gate[lo0]);  // gathered gate input
    float w2 = mask_out[m1];
    w2 = w2 * w2 * sigm(g_out[io1] + b_out_gate[lo1]);
    float w3 = mask_loop[n];
    w3 = w3 * w3 * sigm(g_self[n]);

    float4 pin = *(const float4*)(P_in   + (size_t)ii  * UU + c);
    float4 bin = *(const float4*)(b_in   + (size_t)l_in* UU + c);
    float4 po0 = *(const float4*)(P_out  + (size_t)io0 * UU + c);
    float4 bo0 = *(const float4*)(b_out  + (size_t)lo0 * UU + c);
    float4 po1 = *(const float4*)(P_out  + (size_t)io1 * UU + c);
    float4 bo1 = *(const float4*)(b_out  + (size_t)lo1 * UU + c);
    float4 ps  = *(const float4*)(P_self + (size_t)n   * UU + c);

    float4 r;
    r.x = w0 * (pin.x + bin.x) + w1 * (po0.x + bo0.x) + w2 * (po1.x + bo1.x) + w3 * ps.x;
    r.y = w0 * (pin.y + bin.y) + w1 * (po0.y + bo0.y) + w2 * (po1.y + bo1.y) + w3 * ps.y;
    r.z = w0 * (pin.z + bin.z) + w1 * (po0.z + bo0.z) + w2 * (po1.z + bo1.z) + w3 * ps.z;
    r.w = w0 * (pin.w + bin.w) + w1 * (po0.w + bo0.w) + w2 * (po1.w + bo1.w) + w3 * ps.w;
    r.x = (r.x >= 0.0f) ? r.x : 0.01f * r.x;
    r.y = (r.y >= 0.0f) ? r.y : 0.01f * r.y;
    r.z = (r.z >= 0.0f) ? r.z : 0.01f * r.z;
    r.w = (r.w >= 0.0f) ? r.w : 0.01f * r.w;

    *(float4*)(out + (size_t)n * UU + c) = r;
}

// ---------------------------------------------------------------------------
extern "C" void kernel_launch(void* const* d_in, const int* in_sizes, int n_in,
                              void* d_out, int out_size, void* d_ws, size_t ws_size,
                              hipStream_t stream) {
    const float* enc        = (const float*)d_in[0];
    const int*   arc_in     = (const int*)  d_in[1];
    const int*   arc_out    = (const int*)  d_in[2];
    const int*   lab_in     = (const int*)  d_in[3];
    const int*   lab_out    = (const int*)  d_in[4];
    const float* mask_in    = (const float*)d_in[5];
    const float* mask_out   = (const float*)d_in[6];
    const float* mask_loop  = (const float*)d_in[7];
    const float* V_in       = (const float*)d_in[8];
    const float* b_in       = (const float*)d_in[9];
    const float* V_in_gate  = (const float*)d_in[10];
    const float* b_in_gate  = (const float*)d_in[11];
    const float* V_out      = (const float*)d_in[12];
    const float* b_out      = (const float*)d_in[13];
    const float* V_out_gate = (const float*)d_in[14];
    const float* b_out_gate = (const float*)d_in[15];
    const float* W_self     = (const float*)d_in[16];
    const float* W_self_g   = (const float*)d_in[17];
    float* out = (float*)d_out;

    float* ws     = (float*)d_ws;
    float* P_in   = ws;
    float* P_out  = ws + (size_t)NTOK * UU;
    float* P_self = ws + 2 * (size_t)NTOK * UU;
    float* g_in   = ws + 3 * (size_t)NTOK * UU;
    float* g_out  = g_in + NTOK;
    float* g_self = g_out + NTOK;
    // ws requirement: 3*N*U*4 + 3*N*4 = ~201.7 MB

    gates_kernel<<<NTOK / 4, 256, 0, stream>>>(
        enc, V_in_gate, V_out_gate, W_self_g, g_in, g_out, g_self);

    dim3 grid(NTOK / BM, 12);
    proj_gemm<<<grid, 256, 0, stream>>>(
        enc, V_in, V_out, W_self, P_in, P_out, P_self);

    combine_kernel<<<NTOK / 2, 256, 0, stream>>>(
        P_in, P_out, P_self, g_in, g_out, g_self,
        arc_in, arc_out, lab_in, lab_out,
        mask_in, mask_out, mask_loop,
        b_in, b_in_gate, b_out, b_out_gate, out);
}

// Round 2
// 393.130 us; speedup vs baseline: 1.9165x; 1.9165x over previous
//
#include <hip/hip_runtime.h>
#include <hip/hip_bf16.h>
#include <math.h>

#define NTOK 32768   // N = B*S
#define BB   64
#define SS   512
#define DD   512
#define UU   512
#define DEGQ 2

#define KTOT   1024          // split-W doubled K (hi then lo)
#define BKQ    32
#define NKSTEP (KTOT / BKQ)  // 32

using bf16x8 = __attribute__((ext_vector_type(8))) __bf16;
using f32x4  = __attribute__((ext_vector_type(4))) float;

__device__ __forceinline__ float sigm(float x) { return 1.0f / (1.0f + expf(-x)); }

__device__ __forceinline__ unsigned short bf16bits(float f) {
    __hip_bfloat16 h = __float2bfloat16(f);   // RNE
    return *reinterpret_cast<unsigned short*>(&h);
}
__device__ __forceinline__ float bits2f(unsigned short u) {
    __hip_bfloat16 h = *reinterpret_cast<__hip_bfloat16*>(&u);
    return __bfloat162float(h);
}

#define GLOAD16(gsrc, ldst)                                                        \
    __builtin_amdgcn_global_load_lds(                                              \
        (const __attribute__((address_space(1))) unsigned int*)(gsrc),             \
        (__attribute__((address_space(3))) unsigned int*)(ldst), 16, 0, 0)

// ---------------------------------------------------------------------------
// Kernel 1: convert enc (S,B,D) f32 -> x_bf (N,D) bf16, fused with the three
// gate GEMVs (g_* = x . vgate). One wave per row n; 4 rows per block.
// ---------------------------------------------------------------------------
__global__ __launch_bounds__(256) void conv_gates(
    const float* __restrict__ enc,
    const float* __restrict__ vg_in,
    const float* __restrict__ vg_out,
    const float* __restrict__ vg_self,
    unsigned short* __restrict__ xbf,
    float* __restrict__ g_in, float* __restrict__ g_out, float* __restrict__ g_self)
{
    const int wv   = threadIdx.x >> 6;
    const int lane = threadIdx.x & 63;
    const int n = blockIdx.x * 4 + wv;
    const int b = n >> 9;          // n / S
    const int s = n & 511;         // n % S
    const float* xrow = enc + (size_t)s * (BB * DD) + (size_t)b * DD + lane * 8;

    float4 xa = *(const float4*)(xrow);
    float4 xb = *(const float4*)(xrow + 4);

    // bf16 convert + store (coalesced 16B/lane)
    union { bf16x8 v; unsigned short u[8]; } pk;
    pk.u[0] = bf16bits(xa.x); pk.u[1] = bf16bits(xa.y);
    pk.u[2] = bf16bits(xa.z); pk.u[3] = bf16bits(xa.w);
    pk.u[4] = bf16bits(xb.x); pk.u[5] = bf16bits(xb.y);
    pk.u[6] = bf16bits(xb.z); pk.u[7] = bf16bits(xb.w);
    *(bf16x8*)(xbf + (size_t)n * DD + lane * 8) = pk.v;

    float4 ga = *(const float4*)(vg_in + lane * 8);
    float4 gb = *(const float4*)(vg_in + lane * 8 + 4);
    float di = xa.x*ga.x + xa.y*ga.y + xa.z*ga.z + xa.w*ga.w
             + xb.x*gb.x + xb.y*gb.y + xb.z*gb.z + xb.w*gb.w;

    ga = *(const float4*)(vg_out + lane * 8);
    gb = *(const float4*)(vg_out + lane * 8 + 4);
    float dq = xa.x*ga.x + xa.y*ga.y + xa.z*ga.z + xa.w*ga.w
             + xb.x*gb.x + xb.y*gb.y + xb.z*gb.z + xb.w*gb.w;

    ga = *(const float4*)(vg_self + lane * 8);
    gb = *(const float4*)(vg_self + lane * 8 + 4);
    float ds = xa.x*ga.x + xa.y*ga.y + xa.z*ga.z + xa.w*ga.w
             + xb.x*gb.x + xb.y*gb.y + xb.z*gb.z + xb.w*gb.w;

    #pragma unroll
    for (int off = 32; off > 0; off >>= 1) {
        di += __shfl_xor(di, off);
        dq += __shfl_xor(dq, off);
        ds += __shfl_xor(ds, off);
    }
    if (lane == 0) { g_in[n] = di; g_out[n] = dq; g_self[n] = ds; }
}

// ---------------------------------------------------------------------------
// Kernel 2: W prep. For each of the 3 (D,U) matrices build
// Wt2[mat][u][k]      = bf16(W[k][u])          (hi)
// Wt2[mat][u][512+k]  = bf16(W[k][u] - hi)     (lo residual)
// 32x32 LDS-transposed tiles, both sides coalesced.
// ---------------------------------------------------------------------------
__global__ __launch_bounds__(256) void wprep(
    const float* __restrict__ Vin, const float* __restrict__ Vout,
    const float* __restrict__ Wself, unsigned short* __restrict__ wt2)
{
    const int mat  = blockIdx.x >> 8;      // 256 tiles per matrix
    const int tile = blockIdx.x & 255;
    const int tk = (tile >> 4) * 32;
    const int tu = (tile & 15) * 32;
    const float* W = (mat == 0) ? Vin : (mat == 1) ? Vout : Wself;
    unsigned short* out = wt2 + (size_t)mat * DD * KTOT;

    __shared__ float T[32][33];
    const int r = threadIdx.x >> 3;        // 0..31
    const int c = (threadIdx.x & 7) * 4;   // 0,4,..,28

    float4 v = *(const float4*)(W + (size_t)(tk + r) * UU + tu + c);
    T[r][c] = v.x; T[r][c+1] = v.y; T[r][c+2] = v.z; T[r][c+3] = v.w;
    __syncthreads();

    ushort4 hv, lv;
    unsigned short* hp = &hv.x;
    unsigned short* lp = &lv.x;
    #pragma unroll
    for (int i = 0; i < 4; ++i) {
        float w = T[c + i][r];             // = W[tk+c+i][tu+r]
        unsigned short h = bf16bits(w);
        hp[i] = h;
        lp[i] = bf16bits(w - bits2f(h));
    }
    const size_t rowoff = (size_t)(tu + r) * KTOT;
    *(ushort4*)&out[rowoff + tk + c]       = hv;
    *(ushort4*)&out[rowoff + 512 + tk + c] = lv;
}

// ---------------------------------------------------------------------------
// Kernel 3: bf16 MFMA GEMM, split-W:  P = x_bf @ Wh + x_bf @ Wl  (K=1024).
// 128x128 tile, BK=32, 4 waves (2x2), each wave 64x64 via 4x4 fragments of
// mfma_f32_16x16x32_bf16.  Staging: global_load_lds width 16, lane-major
// 16rowx32k subtiles (per-lane global addr, wave-uniform LDS dest) so both
// staging and ds_read_b128 fragment reads are lane-consecutive (conflict-free).
// grid = (NTOK/128, 12): blockIdx.y -> {mat 0..2} x {4 col tiles}.
// mat==2 (self loop) writes directly into d_out.
// ---------------------------------------------------------------------------
__global__ __launch_bounds__(256) void proj_mfma(
    const unsigned short* __restrict__ xbf,   // (N, 512) bf16
    const unsigned short* __restrict__ wt2,   // (3, 512, 1024) bf16 (u-major)
    float* __restrict__ P_in, float* __restrict__ P_out, float* __restrict__ P_self)
{
    __shared__ unsigned short As[2][4096];    // 8 subtiles x 512 shorts, x2 buf
    __shared__ unsigned short Bs[2][4096];

    const int t    = threadIdx.x;
    const int lane = t & 63;
    const int w    = t >> 6;       // wave 0..3
    const int wm   = w >> 1;       // wave row (0..1)
    const int wn   = w & 1;        // wave col (0..1)

    const int n0  = blockIdx.x * 128;
    const int mat = blockIdx.y >> 2;
    const int u0  = (blockIdx.y & 3) * 128;
    float* P = (mat == 0) ? P_in : (mat == 1) ? P_out : P_self;
    const unsigned short* wt = wt2 + (size_t)mat * DD * KTOT;

    // staging lane geometry: subtile row = lane&15, k-chunk = (lane>>4)*8
    const int lr = lane & 15;
    const int lk = (lane >> 4) * 8;
    // this wave stages A subtiles {2w, 2w+1} and B subtiles {2w, 2w+1}
    const unsigned short* asrc0 = xbf + (size_t)(n0 + 2 * w * 16 + lr) * DD + lk;
    const unsigned short* asrc1 = asrc0 + (size_t)16 * DD;
    const unsigned short* bsrc0 = wt + (size_t)(u0 + 2 * w * 16 + lr) * KTOT + lk;
    const unsigned short* bsrc1 = bsrc0 + (size_t)16 * KTOT;

    f32x4 acc[4][4];
    #pragma unroll
    for (int i = 0; i < 4; ++i)
        #pragma unroll
        for (int j = 0; j < 4; ++j)
            acc[i][j] = (f32x4){0.f, 0.f, 0.f, 0.f};

    // prologue stage of buffer 0, k0 = 0
    {
        GLOAD16(asrc0, &As[0][(2 * w)     * 512]);
        GLOAD16(asrc1, &As[0][(2 * w + 1) * 512]);
        GLOAD16(bsrc0, &Bs[0][(2 * w)     * 512]);
        GLOAD16(bsrc1, &Bs[0][(2 * w + 1) * 512]);
    }
    __syncthreads();

    for (int ks = 0; ks < NKSTEP; ++ks) {
        const int cur = ks & 1;
        if (ks + 1 < NKSTEP) {
            const int k0 = (ks + 1) * BKQ;
            const int ka = k0 & 511;       // A wraps: pass 2 re-reads x
            GLOAD16(asrc0 + ka, &As[cur ^ 1][(2 * w)     * 512]);
            GLOAD16(asrc1 + ka, &As[cur ^ 1][(2 * w + 1) * 512]);
            GLOAD16(bsrc0 + k0, &Bs[cur ^ 1][(2 * w)     * 512]);
            GLOAD16(bsrc1 + k0, &Bs[cur ^ 1][(2 * w + 1) * 512]);
        }
        bf16x8 a[4], b[4];
        #pragma unroll
        for (int i = 0; i < 4; ++i)
            a[i] = *(const bf16x8*)&As[cur][(wm * 4 + i) * 512 + lane * 8];
        #pragma unroll
        for (int j = 0; j < 4; ++j)
            b[j] = *(const bf16x8*)&Bs[cur][(wn * 4 + j) * 512 + lane * 8];
        #pragma unroll
        for (int i = 0; i < 4; ++i)
            #pragma unroll
            for (int j = 0; j < 4; ++j)
                acc[i][j] = __builtin_amdgcn_mfma_f32_16x16x32_bf16(
                    a[i], b[j], acc[i][j], 0, 0, 0);
        __syncthreads();
    }

    // epilogue: C/D layout col = lane&15, row = (lane>>4)*4 + reg  [m89/m91]
    const int cr = (lane >> 4) * 4;
    const int cc = lane & 15;
    #pragma unroll
    for (int i = 0; i < 4; ++i) {
        #pragma unroll
        for (int j = 0; j < 4; ++j) {
            const size_t row = (size_t)n0 + wm * 64 + i * 16 + cr;
            const size_t col = (size_t)u0 + wn * 64 + j * 16 + cc;
            #pragma unroll
            for (int r = 0; r < 4; ++r)
                P[(row + r) * UU + col] = acc[i][j][r];
        }
    }
}

// ---------------------------------------------------------------------------
// Kernel 4: gather + gate + combine + LeakyReLU.  (unchanged semantics)
// P_self aliases `out` (identity-indexed: each element read then written by
// the same thread).
// ---------------------------------------------------------------------------
__global__ __launch_bounds__(256) void combine_kernel(
    const float* __restrict__ P_in,  const float* __restrict__ P_out,
    const float* P_self,
    const float* __restrict__ g_in,  const float* __restrict__ g_out,
    const float* __restrict__ g_self,
    const int* __restrict__ arc_in,  const int* __restrict__ arc_out,
    const int* __restrict__ lab_in,  const int* __restrict__ lab_out,
    const float* __restrict__ mask_in, const float* __restrict__ mask_out,
    const float* __restrict__ mask_loop,
    const float* __restrict__ b_in,  const float* __restrict__ b_in_gate,
    const float* __restrict__ b_out, const float* __restrict__ b_out_gate,
    float* out)
{
    const int t    = threadIdx.x;
    const int rowl = t >> 7;
    const int c    = (t & 127) * 4;
    const int n    = blockIdx.x * 2 + rowl;

    const int l_in = lab_in[n];
    const int ii   = arc_in[n] * SS + arc_in[NTOK + n];
    float w0 = mask_in[n];
    w0 = w0 * w0 * sigm(g_in[n] + b_in_gate[l_in]);     // UN-gathered gate input

    const int m0  = n * DEGQ, m1 = m0 + 1;
    const int lo0 = lab_out[m0], lo1 = lab_out[m1];
    const int io0 = arc_out[m0] * SS + arc_out[NTOK * DEGQ + m0];
    const int io1 = arc_out[m1] * SS + arc_out[NTOK * DEGQ + m1];
    float w1 = mask_out[m0];
    w1 = w1 * w1 * sigm(g_out[io0] + b_out_gate[lo0]);  // gathered gate input
    float w2 = mask_out[m1];
    w2 = w2 * w2 * sigm(g_out[io1] + b_out_gate[lo1]);
    float w3 = mask_loop[n];
    w3 = w3 * w3 * sigm(g_self[n]);

    float4 pin = *(const float4*)(P_in   + (size_t)ii   * UU + c);
    float4 bin = *(const float4*)(b_in   + (size_t)l_in * UU + c);
    float4 po0 = *(const float4*)(P_out  + (size_t)io0  * UU + c);
    float4 bo0 = *(const float4*)(b_out  + (size_t)lo0  * UU + c);
    float4 po1 = *(const float4*)(P_out  + (size_t)io1  * UU + c);
    float4 bo1 = *(const float4*)(b_out  + (size_t)lo1  * UU + c);
    float4 ps  = *(const float4*)(P_self + (size_t)n    * UU + c);

    float4 r;
    r.x = w0 * (pin.x + bin.x) + w1 * (po0.x + bo0.x) + w2 * (po1.x + bo1.x) + w3 * ps.x;
    r.y = w0 * (pin.y + bin.y) + w1 * (po0.y + bo0.y) + w2 * (po1.y + bo1.y) + w3 * ps.y;
    r.z = w0 * (pin.z + bin.z) + w1 * (po0.z + bo0.z) + w2 * (po1.z + bo1.z) + w3 * ps.z;
    r.w = w0 * (pin.w + bin.w) + w1 * (po0.w + bo0.w) + w2 * (po1.w + bo1.w) + w3 * ps.w;
    r.x = (r.x >= 0.0f) ? r.x : 0.01f * r.x;
    r.y = (r.y >= 0.0f) ? r.y : 0.01f * r.y;
    r.z = (r.z >= 0.0f) ? r.z : 0.01f * r.z;
    r.w = (r.w >= 0.0f) ? r.w : 0.01f * r.w;

    *(float4*)(out + (size_t)n * UU + c) = r;
}

// ---------------------------------------------------------------------------
extern "C" void kernel_launch(void* const* d_in, const int* in_sizes, int n_in,
                              void* d_out, int out_size, void* d_ws, size_t ws_size,
                              hipStream_t stream) {
    const float* enc        = (const float*)d_in[0];
    const int*   arc_in     = (const int*)  d_in[1];
    const int*   arc_out    = (const int*)  d_in[2];
    const int*   lab_in     = (const int*)  d_in[3];
    const int*   lab_out    = (const int*)  d_in[4];
    const float* mask_in    = (const float*)d_in[5];
    const float* mask_out   = (const float*)d_in[6];
    const float* mask_loop  = (const float*)d_in[7];
    const float* V_in       = (const float*)d_in[8];
    const float* b_in       = (const float*)d_in[9];
    const float* V_in_gate  = (const float*)d_in[10];
    const float* b_in_gate  = (const float*)d_in[11];
    const float* V_out      = (const float*)d_in[12];
    const float* b_out      = (const float*)d_in[13];
    const float* V_out_gate = (const float*)d_in[14];
    const float* b_out_gate = (const float*)d_in[15];
    const float* W_self     = (const float*)d_in[16];
    const float* W_self_g   = (const float*)d_in[17];
    float* out = (float*)d_out;

    // workspace layout (~164 MB)
    float* P_in  = (float*)d_ws;
    float* P_out = P_in + (size_t)NTOK * UU;                 // +64 MB
    float* g_in   = P_out + (size_t)NTOK * UU;               // +64 MB
    float* g_out  = g_in + NTOK;
    float* g_self = g_out + NTOK;
    unsigned short* xbf = (unsigned short*)(g_self + NTOK);  // 32 MB
    unsigned short* wt2 = xbf + (size_t)NTOK * DD;           // 3 MB

    conv_gates<<<NTOK / 4, 256, 0, stream>>>(
        enc, V_in_gate, V_out_gate, W_self_g, xbf, g_in, g_out, g_self);

    wprep<<<768, 256, 0, stream>>>(V_in, V_out, W_self, wt2);

    dim3 grid(NTOK / 128, 12);
    proj_mfma<<<grid, 256, 0, stream>>>(xbf, wt2, P_in, P_out, /*P_self=*/out);

    combine_kernel<<<NTOK / 2, 256, 0, stream>>>(
        P_in, P_out, /*P_self=*/out, g_in, g_out, g_self,
        arc_in, arc_out, lab_in, lab_out,
        mask_in, mask_out, mask_loop,
        b_in, b_in_gate, b_out, b_out_gate, out);
}